// Round 1
// baseline (618.898 us; speedup 1.0000x reference)
//
#include <hip/hip_runtime.h>
#include <hip/hip_bf16.h>

#define N_NODES 50000
#define N_EDGES 600000
#define N_GRAPHS 100
// IN=128, HID=128, OUT=64, K=2 -> concat K-dim = 384

// ---------------- degree / norm ----------------
__global__ void degk(const int* __restrict__ dst, int* __restrict__ deg, int n) {
    int i = blockIdx.x * 256 + threadIdx.x;
    if (i < n) atomicAdd(&deg[dst[i]], 1);
}

__global__ void normk(const int* __restrict__ deg, float* __restrict__ norm, int n) {
    int i = blockIdx.x * 256 + threadIdx.x;
    if (i < n) {
        float d = fmaxf((float)deg[i], 1.0f);
        norm[i] = 1.0f / sqrtf(d);
    }
}

// ---------------- hierarchical exclusive scan (row offsets) ----------------
__global__ __launch_bounds__(1024) void scan1(const int* __restrict__ deg,
                                              int* __restrict__ row_off,
                                              int* __restrict__ partial, int n) {
    __shared__ int buf[1024];
    int i = blockIdx.x * 1024 + threadIdx.x;
    int v = (i < n) ? deg[i] : 0;
    buf[threadIdx.x] = v;
    __syncthreads();
    for (int off = 1; off < 1024; off <<= 1) {
        int t = (threadIdx.x >= off) ? buf[threadIdx.x - off] : 0;
        __syncthreads();
        buf[threadIdx.x] += t;
        __syncthreads();
    }
    if (i < n) row_off[i + 1] = buf[threadIdx.x];  // local inclusive
    if (threadIdx.x == 1023) partial[blockIdx.x] = buf[1023];
}

__global__ void scan2(int* __restrict__ partial, int nchunks) {
    int lane = threadIdx.x;  // 64 threads, nchunks <= 64
    int v = (lane < nchunks) ? partial[lane] : 0;
    for (int off = 1; off < 64; off <<= 1) {
        int t = __shfl_up(v, off, 64);
        if (lane >= off) v += t;
    }
    int ex = __shfl_up(v, 1, 64);
    if (lane == 0) ex = 0;
    if (lane < nchunks) partial[lane] = ex;
}

__global__ void scan3(int* __restrict__ row_off, const int* __restrict__ partial, int n) {
    int i = blockIdx.x * 256 + threadIdx.x;
    if (i == 0) row_off[0] = 0;
    if (i < n) row_off[i + 1] += partial[i >> 10];
}

// ---------------- CSR scatter ----------------
__global__ void scatterk(const int* __restrict__ src, const int* __restrict__ dst,
                         const int* __restrict__ row_off, int* __restrict__ cursor,
                         int* __restrict__ csr_src, int n) {
    int e = blockIdx.x * 256 + threadIdx.x;
    if (e >= n) return;
    int d = dst[e];
    int pos = atomicAdd(&cursor[d], 1);
    csr_src[row_off[d] + pos] = src[e];
}

// ---------------- SpMM: out[d] = norm[d] * sum_{s in N(d)} norm[s]*in[s], 128 feats ----------------
__global__ __launch_bounds__(256) void spmm128(const float* __restrict__ in,
                                               float* __restrict__ out,
                                               const float* __restrict__ norm,
                                               const int* __restrict__ row_off,
                                               const int* __restrict__ csr_src, int n) {
    int wave = threadIdx.x >> 6;
    int lane = threadIdx.x & 63;
    int node = blockIdx.x * 4 + wave;
    if (node >= n) return;
    int e0 = row_off[node], e1 = row_off[node + 1];
    const float2* in2 = (const float2*)in;
    float2 acc = make_float2(0.f, 0.f);
    for (int e = e0; e < e1; e++) {
        int s = csr_src[e];
        float ns = norm[s];
        float2 v = in2[(size_t)s * 64 + lane];
        acc.x += ns * v.x;
        acc.y += ns * v.y;
    }
    float nd = norm[node];
    float2* out2 = (float2*)out;
    out2[(size_t)node * 64 + lane] = make_float2(acc.x * nd, acc.y * nd);
}

// ---------------- concat-GEMM: out = relu([f0|f1|f2] @ W + b), A-ld = 128, K = 384 ----------------
template <int BN>
__global__ __launch_bounds__(256) void gemm_concat(const float* __restrict__ f0,
                                                   const float* __restrict__ f1,
                                                   const float* __restrict__ f2,
                                                   const float* __restrict__ W,
                                                   const float* __restrict__ bias,
                                                   float* __restrict__ out, int M) {
    constexpr int BM = 64, BK = 16;
    constexpr int TN = 4;
    constexpr int NTX = BN / TN;    // 32 (BN=128) or 16 (BN=64)
    constexpr int NTY = 256 / NTX;  // 8 or 16
    constexpr int TM = BM / NTY;    // 8 or 4

    __shared__ float As[BK][BM];  // transposed: As[k][m]
    __shared__ float Bs[BK][BN];

    int tid = threadIdx.x;
    int tx = tid % NTX, ty = tid / NTX;
    int row0 = blockIdx.x * BM;

    float acc[TM][TN] = {};
    const float* feats[3] = {f0, f1, f2};

    for (int kc = 0; kc < 24; kc++) {
        const float* srcA = feats[kc >> 3];
        int koff = (kc & 7) * BK;
        // stage A: 64 rows x 16 k = 256 float4; tid -> m = tid/4, kk4 = (tid%4)*4
        {
            int m = tid >> 2;
            int kk4 = (tid & 3) * 4;
            int row = row0 + m;
            float4 v = make_float4(0.f, 0.f, 0.f, 0.f);
            if (row < M) v = *(const float4*)(srcA + (size_t)row * 128 + koff + kk4);
            As[kk4 + 0][m] = v.x;
            As[kk4 + 1][m] = v.y;
            As[kk4 + 2][m] = v.z;
            As[kk4 + 3][m] = v.w;
        }
        // stage B: BK x BN from W (row-major 384 x BN)
        {
            const float* wsrc = W + (size_t)(kc * BK) * BN;
            for (int idx = tid; idx < BK * BN / 4; idx += 256) {
                int kk = idx / (BN / 4);
                int n4 = (idx % (BN / 4)) * 4;
                *(float4*)&Bs[kk][n4] = *(const float4*)(wsrc + kk * BN + n4);
            }
        }
        __syncthreads();
#pragma unroll
        for (int kk = 0; kk < BK; kk++) {
            float a[TM], b[TN];
#pragma unroll
            for (int i = 0; i < TM; i += 4) {
                float4 t = *(const float4*)&As[kk][ty * TM + i];
                a[i] = t.x; a[i + 1] = t.y; a[i + 2] = t.z; a[i + 3] = t.w;
            }
            float4 tb = *(const float4*)&Bs[kk][tx * TN];
            b[0] = tb.x; b[1] = tb.y; b[2] = tb.z; b[3] = tb.w;
#pragma unroll
            for (int i = 0; i < TM; i++)
#pragma unroll
                for (int j = 0; j < TN; j++) acc[i][j] += a[i] * b[j];
        }
        __syncthreads();
    }
#pragma unroll
    for (int i = 0; i < TM; i++) {
        int row = row0 + ty * TM + i;
        if (row >= M) continue;
        float4 o;
        o.x = fmaxf(acc[i][0] + bias[tx * TN + 0], 0.f);
        o.y = fmaxf(acc[i][1] + bias[tx * TN + 1], 0.f);
        o.z = fmaxf(acc[i][2] + bias[tx * TN + 2], 0.f);
        o.w = fmaxf(acc[i][3] + bias[tx * TN + 3], 0.f);
        *(float4*)(out + (size_t)row * BN + tx * TN) = o;
    }
}

// ---------------- graph boundary detection (graph_id sorted) ----------------
__global__ void bounds(const int* __restrict__ gid, int* __restrict__ gstart,
                       int* __restrict__ gend, int n) {
    int i = blockIdx.x * 256 + threadIdx.x;
    if (i >= n) return;
    int g = gid[i];
    if (i == 0 || gid[i - 1] != g) gstart[g] = i;
    if (i == n - 1 || gid[i + 1] != g) gend[g] = i + 1;
}

// ---------------- per-graph max pool, 64 feats ----------------
__global__ void maxpool(const float* __restrict__ hF, const int* __restrict__ gstart,
                        const int* __restrict__ gend, float* __restrict__ out) {
    int g = blockIdx.x, t = threadIdx.x;  // 64 threads
    int s = gstart[g], e = gend[g];
    float m0 = -__builtin_inff(), m1 = -__builtin_inff();
    int i = s;
    for (; i + 1 < e; i += 2) {
        m0 = fmaxf(m0, hF[(size_t)i * 64 + t]);
        m1 = fmaxf(m1, hF[(size_t)(i + 1) * 64 + t]);
    }
    if (i < e) m0 = fmaxf(m0, hF[(size_t)i * 64 + t]);
    out[g * 64 + t] = fmaxf(m0, m1);
}

extern "C" void kernel_launch(void* const* d_in, const int* in_sizes, int n_in,
                              void* d_out, int out_size, void* d_ws, size_t ws_size,
                              hipStream_t stream) {
    const float* x  = (const float*)d_in[0];
    const float* W1 = (const float*)d_in[1];
    const float* b1 = (const float*)d_in[2];
    const float* W2 = (const float*)d_in[3];
    const float* b2 = (const float*)d_in[4];
    const int* src  = (const int*)d_in[5];
    const int* dst  = (const int*)d_in[6];
    const int* gid  = (const int*)d_in[7];
    float* out = (float*)d_out;

    char* ws = (char*)d_ws;
    size_t off = 0;
    auto take = [&](size_t bytes) {
        void* p = ws + off;
        off = (off + bytes + 255) & ~(size_t)255;
        return p;
    };
    int* deg     = (int*)take((size_t)N_NODES * 4);
    int* cursor  = (int*)take((size_t)N_NODES * 4);
    int* gstart  = (int*)take((size_t)N_GRAPHS * 4);
    int* gend    = (int*)take((size_t)N_GRAPHS * 4);
    size_t zero_bytes = off;  // everything above must start at 0 each launch
    float* norm  = (float*)take((size_t)N_NODES * 4);
    int* row_off = (int*)take((size_t)(N_NODES + 1) * 4);
    int* partial = (int*)take(64 * 4);
    int* csr_src = (int*)take((size_t)N_EDGES * 4);
    float* h1    = (float*)take((size_t)N_NODES * 128 * 4);
    float* h2    = (float*)take((size_t)N_NODES * 128 * 4);
    float* hL1   = (float*)take((size_t)N_NODES * 128 * 4);
    float* hF    = (float*)take((size_t)N_NODES * 64 * 4);
    (void)ws_size; (void)in_sizes; (void)n_in; (void)out_size;

    hipMemsetAsync(d_ws, 0, zero_bytes, stream);

    degk<<<(N_EDGES + 255) / 256, 256, 0, stream>>>(dst, deg, N_EDGES);
    normk<<<(N_NODES + 255) / 256, 256, 0, stream>>>(deg, norm, N_NODES);

    int nchunks = (N_NODES + 1023) / 1024;
    scan1<<<nchunks, 1024, 0, stream>>>(deg, row_off, partial, N_NODES);
    scan2<<<1, 64, 0, stream>>>(partial, nchunks);
    scan3<<<(N_NODES + 255) / 256, 256, 0, stream>>>(row_off, partial, N_NODES);

    scatterk<<<(N_EDGES + 255) / 256, 256, 0, stream>>>(src, dst, row_off, cursor, csr_src, N_EDGES);
    bounds<<<(N_NODES + 255) / 256, 256, 0, stream>>>(gid, gstart, gend, N_NODES);

    int spmm_grid = (N_NODES + 3) / 4;
    // layer 1
    spmm128<<<spmm_grid, 256, 0, stream>>>(x, h1, norm, row_off, csr_src, N_NODES);
    spmm128<<<spmm_grid, 256, 0, stream>>>(h1, h2, norm, row_off, csr_src, N_NODES);
    gemm_concat<128><<<(N_NODES + 63) / 64, 256, 0, stream>>>(x, h1, h2, W1, b1, hL1, N_NODES);
    // layer 2
    spmm128<<<spmm_grid, 256, 0, stream>>>(hL1, h1, norm, row_off, csr_src, N_NODES);
    spmm128<<<spmm_grid, 256, 0, stream>>>(h1, h2, norm, row_off, csr_src, N_NODES);
    gemm_concat<64><<<(N_NODES + 63) / 64, 256, 0, stream>>>(hL1, h1, h2, W2, b2, hF, N_NODES);
    // readout
    maxpool<<<N_GRAPHS, 64, 0, stream>>>(hF, gstart, gend, out);
}

// Round 2
// 403.494 us; speedup vs baseline: 1.5338x; 1.5338x over previous
//
#include <hip/hip_runtime.h>
#include <hip/hip_bf16.h>

#define N_NODES 50000
#define N_EDGES 600000
#define N_GRAPHS 100
#define M_PAD 50176  // 392 * 128

typedef __bf16 bf16_t;
typedef __attribute__((ext_vector_type(8))) __bf16 bf16x8;
typedef __attribute__((ext_vector_type(2))) __bf16 bf16x2;
typedef __attribute__((ext_vector_type(4))) float f32x4;

// ---------------- degree / norm ----------------
__global__ void degk(const int* __restrict__ dst, int* __restrict__ deg, int n) {
    int i = blockIdx.x * 256 + threadIdx.x;
    if (i < n) atomicAdd(&deg[dst[i]], 1);
}

__global__ void normk(const int* __restrict__ deg, float* __restrict__ norm, int n) {
    int i = blockIdx.x * 256 + threadIdx.x;
    if (i < n) {
        float d = fmaxf((float)deg[i], 1.0f);
        norm[i] = 1.0f / sqrtf(d);
    }
}

// ---------------- hierarchical exclusive scan (row offsets) ----------------
__global__ __launch_bounds__(1024) void scan1(const int* __restrict__ deg,
                                              int* __restrict__ row_off,
                                              int* __restrict__ partial, int n) {
    __shared__ int buf[1024];
    int i = blockIdx.x * 1024 + threadIdx.x;
    int v = (i < n) ? deg[i] : 0;
    buf[threadIdx.x] = v;
    __syncthreads();
    for (int off = 1; off < 1024; off <<= 1) {
        int t = (threadIdx.x >= off) ? buf[threadIdx.x - off] : 0;
        __syncthreads();
        buf[threadIdx.x] += t;
        __syncthreads();
    }
    if (i < n) row_off[i + 1] = buf[threadIdx.x];
    if (threadIdx.x == 1023) partial[blockIdx.x] = buf[1023];
}

__global__ void scan2(int* __restrict__ partial, int nchunks) {
    int lane = threadIdx.x;
    int v = (lane < nchunks) ? partial[lane] : 0;
    for (int off = 1; off < 64; off <<= 1) {
        int t = __shfl_up(v, off, 64);
        if (lane >= off) v += t;
    }
    int ex = __shfl_up(v, 1, 64);
    if (lane == 0) ex = 0;
    if (lane < nchunks) partial[lane] = ex;
}

__global__ void scan3(int* __restrict__ row_off, const int* __restrict__ partial, int n) {
    int i = blockIdx.x * 256 + threadIdx.x;
    if (i == 0) row_off[0] = 0;
    if (i < n) row_off[i + 1] += partial[i >> 10];
}

// ---------------- CSR scatter ----------------
__global__ void scatterk(const int* __restrict__ src, const int* __restrict__ dst,
                         const int* __restrict__ row_off, int* __restrict__ cursor,
                         int* __restrict__ csr_src, int n) {
    int e = blockIdx.x * 256 + threadIdx.x;
    if (e >= n) return;
    int d = dst[e];
    int pos = atomicAdd(&cursor[d], 1);
    csr_src[row_off[d] + pos] = src[e];
}

// ---------------- prescale: xb = bf16(x), xs = bf16(x*norm) ----------------
__global__ void prescale(const float* __restrict__ x, const float* __restrict__ norm,
                         bf16_t* __restrict__ xb, bf16_t* __restrict__ xs, int n) {
    int i = blockIdx.x * 256 + threadIdx.x;
    if (i >= n * 64) return;
    int node = i >> 6;
    int c = (i & 63) * 2;
    float2 v = *(const float2*)(x + (size_t)node * 128 + c);
    float nd = norm[node];
    bf16x2 vb; vb[0] = (bf16_t)v.x; vb[1] = (bf16_t)v.y;
    bf16x2 vs; vs[0] = (bf16_t)(v.x * nd); vs[1] = (bf16_t)(v.y * nd);
    *(bf16x2*)(xb + (size_t)node * 128 + c) = vb;
    *(bf16x2*)(xs + (size_t)node * 128 + c) = vs;
}

// ---------------- W permute to MFMA B-fragment layout + bf16 ----------------
// B-frag: lane (q*16+ln) holds B[kt*32 + q*8 + j][nt*16 + ln], j=0..7 contiguous.
__global__ void permW(const float* __restrict__ W, bf16_t* __restrict__ Wp, int K, int N) {
    int i = blockIdx.x * 256 + threadIdx.x;
    if (i >= K * N) return;
    int k = i / N, n = i - k * N;
    int kt = k >> 5, q = (k >> 3) & 3, j = k & 7;
    int nt = n >> 4, ln = n & 15;
    int lane = q * 16 + ln;
    Wp[(((size_t)kt * (N >> 4) + nt) * 64 + lane) * 8 + j] = (bf16_t)W[i];
}

// ---------------- SpMM (bf16 in, fp32 acc): cur = norm[d] * sum_{s} in[s] ----------------
template <bool SCALED>
__global__ __launch_bounds__(256) void spmm_bf16(const bf16_t* __restrict__ in,
                                                 bf16_t* __restrict__ out_c,
                                                 bf16_t* __restrict__ out_s,
                                                 const float* __restrict__ norm,
                                                 const int* __restrict__ row_off,
                                                 const int* __restrict__ csr_src, int n) {
    int wave = threadIdx.x >> 6;
    int lane = threadIdx.x & 63;
    int node = blockIdx.x * 4 + wave;
    if (node >= n) return;
    int e0 = row_off[node], e1 = row_off[node + 1];
    int c = lane * 2;
    float ax = 0.f, ay = 0.f;
    int e = e0;
    for (; e + 4 <= e1; e += 4) {
        int s0 = csr_src[e + 0];
        int s1 = csr_src[e + 1];
        int s2 = csr_src[e + 2];
        int s3 = csr_src[e + 3];
        bf16x2 v0 = *(const bf16x2*)(in + (size_t)s0 * 128 + c);
        bf16x2 v1 = *(const bf16x2*)(in + (size_t)s1 * 128 + c);
        bf16x2 v2 = *(const bf16x2*)(in + (size_t)s2 * 128 + c);
        bf16x2 v3 = *(const bf16x2*)(in + (size_t)s3 * 128 + c);
        ax += (float)v0[0] + (float)v1[0] + (float)v2[0] + (float)v3[0];
        ay += (float)v0[1] + (float)v1[1] + (float)v2[1] + (float)v3[1];
    }
    for (; e < e1; e++) {
        int s = csr_src[e];
        bf16x2 v = *(const bf16x2*)(in + (size_t)s * 128 + c);
        ax += (float)v[0];
        ay += (float)v[1];
    }
    float nd = norm[node];
    float cx = ax * nd, cy = ay * nd;
    bf16x2 o; o[0] = (bf16_t)cx; o[1] = (bf16_t)cy;
    *(bf16x2*)(out_c + (size_t)node * 128 + c) = o;
    if (SCALED) {
        bf16x2 s2v; s2v[0] = (bf16_t)(cx * nd); s2v[1] = (bf16_t)(cy * nd);
        *(bf16x2*)(out_s + (size_t)node * 128 + c) = s2v;
    }
}

// ---------------- MFMA concat-GEMM: out = relu([f0|f1|f2] @ W + b) ----------------
// NT = N/16 (8 for N=128, 4 for N=64). No LDS: A-frags and pre-permuted B-frags
// are direct 16B global loads (A rows unique per block; B broadcast -> L1 hits).
template <int NT, bool LAYER1>
__global__ __launch_bounds__(256) void gemm_mfma(const bf16_t* __restrict__ f0,
                                                 const bf16_t* __restrict__ f1,
                                                 const bf16_t* __restrict__ f2,
                                                 const bf16_t* __restrict__ Wp,
                                                 const float* __restrict__ bias,
                                                 const float* __restrict__ norm,
                                                 bf16_t* __restrict__ out_b,
                                                 bf16_t* __restrict__ out_s,
                                                 float* __restrict__ out_f, int M) {
    int wave = threadIdx.x >> 6;
    int lane = threadIdx.x & 63;
    int q = lane >> 4, ln = lane & 15;
    int row0 = blockIdx.x * 128 + wave * 32;

    f32x4 acc[2][NT] = {};
    const bf16_t* feats[3] = {f0, f1, f2};
    const bf16x8* Wf = (const bf16x8*)Wp;

#pragma unroll
    for (int kc = 0; kc < 12; kc++) {
        const bf16_t* A = feats[kc >> 2] + (size_t)(kc & 3) * 32 + q * 8;
        bf16x8 a0 = *(const bf16x8*)(A + (size_t)(row0 + ln) * 128);
        bf16x8 a1 = *(const bf16x8*)(A + (size_t)(row0 + 16 + ln) * 128);
        const bf16x8* Bp = Wf + (size_t)kc * NT * 64 + lane;
#pragma unroll
        for (int nt = 0; nt < NT; nt++) {
            bf16x8 b = Bp[nt * 64];
            acc[0][nt] = __builtin_amdgcn_mfma_f32_16x16x32_bf16(a0, b, acc[0][nt], 0, 0, 0);
            acc[1][nt] = __builtin_amdgcn_mfma_f32_16x16x32_bf16(a1, b, acc[1][nt], 0, 0, 0);
        }
    }

    float bv[NT];
#pragma unroll
    for (int nt = 0; nt < NT; nt++) bv[nt] = bias[nt * 16 + ln];

#pragma unroll
    for (int mt = 0; mt < 2; mt++) {
#pragma unroll
        for (int r = 0; r < 4; r++) {
            int row = row0 + mt * 16 + q * 4 + r;
            if (row >= M) continue;
            float nd = LAYER1 ? norm[row] : 0.f;
#pragma unroll
            for (int nt = 0; nt < NT; nt++) {
                int col = nt * 16 + ln;
                float val = fmaxf(acc[mt][nt][r] + bv[nt], 0.f);
                if (LAYER1) {
                    out_b[(size_t)row * 128 + col] = (bf16_t)val;
                    out_s[(size_t)row * 128 + col] = (bf16_t)(val * nd);
                } else {
                    out_f[(size_t)row * 64 + col] = val;
                }
            }
        }
    }
}

// ---------------- graph boundary detection (graph_id sorted) ----------------
__global__ void bounds(const int* __restrict__ gid, int* __restrict__ gstart,
                       int* __restrict__ gend, int n) {
    int i = blockIdx.x * 256 + threadIdx.x;
    if (i >= n) return;
    int g = gid[i];
    if (i == 0 || gid[i - 1] != g) gstart[g] = i;
    if (i == n - 1 || gid[i + 1] != g) gend[g] = i + 1;
}

// ---------------- per-graph max pool, 64 feats ----------------
__global__ void maxpool(const float* __restrict__ hF, const int* __restrict__ gstart,
                        const int* __restrict__ gend, float* __restrict__ out) {
    int g = blockIdx.x, t = threadIdx.x;
    int s = gstart[g], e = gend[g];
    float m0 = -__builtin_inff(), m1 = -__builtin_inff();
    int i = s;
    for (; i + 1 < e; i += 2) {
        m0 = fmaxf(m0, hF[(size_t)i * 64 + t]);
        m1 = fmaxf(m1, hF[(size_t)(i + 1) * 64 + t]);
    }
    if (i < e) m0 = fmaxf(m0, hF[(size_t)i * 64 + t]);
    out[g * 64 + t] = fmaxf(m0, m1);
}

extern "C" void kernel_launch(void* const* d_in, const int* in_sizes, int n_in,
                              void* d_out, int out_size, void* d_ws, size_t ws_size,
                              hipStream_t stream) {
    const float* x  = (const float*)d_in[0];
    const float* W1 = (const float*)d_in[1];
    const float* b1 = (const float*)d_in[2];
    const float* W2 = (const float*)d_in[3];
    const float* b2 = (const float*)d_in[4];
    const int* src  = (const int*)d_in[5];
    const int* dst  = (const int*)d_in[6];
    const int* gid  = (const int*)d_in[7];
    float* out = (float*)d_out;

    char* ws = (char*)d_ws;
    size_t off = 0;
    auto take = [&](size_t bytes) {
        void* p = ws + off;
        off = (off + bytes + 255) & ~(size_t)255;
        return p;
    };
    int* deg     = (int*)take((size_t)N_NODES * 4);
    int* cursor  = (int*)take((size_t)N_NODES * 4);
    int* gstart  = (int*)take((size_t)N_GRAPHS * 4);
    int* gend    = (int*)take((size_t)N_GRAPHS * 4);
    size_t zero_bytes = off;
    float* norm  = (float*)take((size_t)N_NODES * 4);
    int* row_off = (int*)take((size_t)(N_NODES + 1) * 4);
    int* partial = (int*)take(64 * 4);
    int* csr_src = (int*)take((size_t)N_EDGES * 4);
    bf16_t* Wp1  = (bf16_t*)take((size_t)384 * 128 * 2);
    bf16_t* Wp2  = (bf16_t*)take((size_t)384 * 64 * 2);
    // 6 reusable bf16 feature buffers, M_PAD x 128 each (B0 doubles as fp32 M_PAD x 64)
    bf16_t* B0 = (bf16_t*)take((size_t)M_PAD * 128 * 2);  // xb      -> hF (fp32 64c)
    bf16_t* B1 = (bf16_t*)take((size_t)M_PAD * 128 * 2);  // xs      -> hL1s
    bf16_t* B2 = (bf16_t*)take((size_t)M_PAD * 128 * 2);  // c1b     -> d1b
    bf16_t* B3 = (bf16_t*)take((size_t)M_PAD * 128 * 2);  // c2b     -> d2b
    bf16_t* B4 = (bf16_t*)take((size_t)M_PAD * 128 * 2);  // u1b     -> u2b
    bf16_t* B5 = (bf16_t*)take((size_t)M_PAD * 128 * 2);  // hL1b
    (void)ws_size; (void)in_sizes; (void)n_in; (void)out_size;

    hipMemsetAsync(d_ws, 0, zero_bytes, stream);

    degk<<<(N_EDGES + 255) / 256, 256, 0, stream>>>(dst, deg, N_EDGES);
    normk<<<(N_NODES + 255) / 256, 256, 0, stream>>>(deg, norm, N_NODES);

    int nchunks = (N_NODES + 1023) / 1024;
    scan1<<<nchunks, 1024, 0, stream>>>(deg, row_off, partial, N_NODES);
    scan2<<<1, 64, 0, stream>>>(partial, nchunks);
    scan3<<<(N_NODES + 255) / 256, 256, 0, stream>>>(row_off, partial, N_NODES);
    scatterk<<<(N_EDGES + 255) / 256, 256, 0, stream>>>(src, dst, row_off, cursor, csr_src, N_EDGES);
    bounds<<<(N_NODES + 255) / 256, 256, 0, stream>>>(gid, gstart, gend, N_NODES);

    prescale<<<(N_NODES * 64 + 255) / 256, 256, 0, stream>>>(x, norm, B0, B1, N_NODES);
    permW<<<(384 * 128 + 255) / 256, 256, 0, stream>>>(W1, Wp1, 384, 128);
    permW<<<(384 * 64 + 255) / 256, 256, 0, stream>>>(W2, Wp2, 384, 64);

    int spmm_grid = (N_NODES + 3) / 4;
    int gemm_grid = M_PAD / 128;  // 392
    // layer 1: hops
    spmm_bf16<true><<<spmm_grid, 256, 0, stream>>>(B1, B2, B4, norm, row_off, csr_src, N_NODES);
    spmm_bf16<false><<<spmm_grid, 256, 0, stream>>>(B4, B3, nullptr, norm, row_off, csr_src, N_NODES);
    // layer 1: GEMM -> hL1b (B5), hL1s (B1)
    gemm_mfma<8, true><<<gemm_grid, 256, 0, stream>>>(B0, B2, B3, Wp1, b1, norm, B5, B1, nullptr, N_NODES);
    // layer 2: hops
    spmm_bf16<true><<<spmm_grid, 256, 0, stream>>>(B1, B2, B4, norm, row_off, csr_src, N_NODES);
    spmm_bf16<false><<<spmm_grid, 256, 0, stream>>>(B4, B3, nullptr, norm, row_off, csr_src, N_NODES);
    // layer 2: GEMM -> hF (B0 as fp32, 64 cols)
    gemm_mfma<4, false><<<gemm_grid, 256, 0, stream>>>(B5, B2, B3, Wp2, b2, nullptr, nullptr, nullptr, (float*)B0, N_NODES);
    // readout
    maxpool<<<N_GRAPHS, 64, 0, stream>>>((const float*)B0, gstart, gend, out);
}

// Round 3
// 342.497 us; speedup vs baseline: 1.8070x; 1.1781x over previous
//
#include <hip/hip_runtime.h>
#include <hip/hip_bf16.h>

#define N_NODES 50000
#define N_EDGES 600000
#define N_GRAPHS 100
#define M_PAD 50176  // 392 * 128

typedef __bf16 bf16_t;
typedef __attribute__((ext_vector_type(8))) __bf16 bf16x8;
typedef __attribute__((ext_vector_type(2))) __bf16 bf16x2;
typedef __attribute__((ext_vector_type(4))) float f32x4;

// ---------------- degree / norm ----------------
__global__ void degk(const int* __restrict__ dst, int* __restrict__ deg, int n) {
    int i = blockIdx.x * 256 + threadIdx.x;
    if (i < n) atomicAdd(&deg[dst[i]], 1);
}

__global__ void normk(const int* __restrict__ deg, float* __restrict__ norm, int n) {
    int i = blockIdx.x * 256 + threadIdx.x;
    if (i < n) {
        float d = fmaxf((float)deg[i], 1.0f);
        norm[i] = 1.0f / sqrtf(d);
    }
}

// ---------------- hierarchical exclusive scan (row offsets) ----------------
__global__ __launch_bounds__(1024) void scan1(const int* __restrict__ deg,
                                              int* __restrict__ row_off,
                                              int* __restrict__ partial, int n) {
    __shared__ int buf[1024];
    int i = blockIdx.x * 1024 + threadIdx.x;
    int v = (i < n) ? deg[i] : 0;
    buf[threadIdx.x] = v;
    __syncthreads();
    for (int off = 1; off < 1024; off <<= 1) {
        int t = (threadIdx.x >= off) ? buf[threadIdx.x - off] : 0;
        __syncthreads();
        buf[threadIdx.x] += t;
        __syncthreads();
    }
    if (i < n) row_off[i + 1] = buf[threadIdx.x];
    if (threadIdx.x == 1023) partial[blockIdx.x] = buf[1023];
}

__global__ void scan2(int* __restrict__ partial, int nchunks) {
    int lane = threadIdx.x;
    int v = (lane < nchunks) ? partial[lane] : 0;
    for (int off = 1; off < 64; off <<= 1) {
        int t = __shfl_up(v, off, 64);
        if (lane >= off) v += t;
    }
    int ex = __shfl_up(v, 1, 64);
    if (lane == 0) ex = 0;
    if (lane < nchunks) partial[lane] = ex;
}

__global__ void scan3(int* __restrict__ row_off, const int* __restrict__ partial, int n) {
    int i = blockIdx.x * 256 + threadIdx.x;
    if (i == 0) row_off[0] = 0;
    if (i < n) row_off[i + 1] += partial[i >> 10];
}

// ---------------- CSR scatter ----------------
__global__ void scatterk(const int* __restrict__ src, const int* __restrict__ dst,
                         const int* __restrict__ row_off, int* __restrict__ cursor,
                         int* __restrict__ csr_src, int n) {
    int e = blockIdx.x * 256 + threadIdx.x;
    if (e >= n) return;
    int d = dst[e];
    int pos = atomicAdd(&cursor[d], 1);
    csr_src[row_off[d] + pos] = src[e];
}

// ---------------- prescale: xb = bf16(x), xs = bf16(x*norm) ----------------
__global__ void prescale(const float* __restrict__ x, const float* __restrict__ norm,
                         bf16_t* __restrict__ xb, bf16_t* __restrict__ xs, int n) {
    int i = blockIdx.x * 256 + threadIdx.x;
    if (i >= n * 64) return;
    int node = i >> 6;
    int c = (i & 63) * 2;
    float2 v = *(const float2*)(x + (size_t)node * 128 + c);
    float nd = norm[node];
    bf16x2 vb; vb[0] = (bf16_t)v.x; vb[1] = (bf16_t)v.y;
    bf16x2 vs; vs[0] = (bf16_t)(v.x * nd); vs[1] = (bf16_t)(v.y * nd);
    *(bf16x2*)(xb + (size_t)node * 128 + c) = vb;
    *(bf16x2*)(xs + (size_t)node * 128 + c) = vs;
}

// ---------------- W permute to MFMA B-fragment layout + bf16 ----------------
__global__ void permW(const float* __restrict__ W, bf16_t* __restrict__ Wp, int K, int N) {
    int i = blockIdx.x * 256 + threadIdx.x;
    if (i >= K * N) return;
    int k = i / N, n = i - k * N;
    int kt = k >> 5, q = (k >> 3) & 3, j = k & 7;
    int nt = n >> 4, ln = n & 15;
    int lane = q * 16 + ln;
    Wp[(((size_t)kt * (N >> 4) + nt) * 64 + lane) * 8 + j] = (bf16_t)W[i];
}

// ---------------- SpMM (bf16 in, fp32 acc): cur = norm[d] * sum_{s} in[s] ----------------
template <bool SCALED>
__global__ __launch_bounds__(256) void spmm_bf16(const bf16_t* __restrict__ in,
                                                 bf16_t* __restrict__ out_c,
                                                 bf16_t* __restrict__ out_s,
                                                 const float* __restrict__ norm,
                                                 const int* __restrict__ row_off,
                                                 const int* __restrict__ csr_src, int n) {
    int wave = threadIdx.x >> 6;
    int lane = threadIdx.x & 63;
    int node = blockIdx.x * 4 + wave;
    if (node >= n) return;
    int e0 = row_off[node], e1 = row_off[node + 1];
    int c = lane * 2;
    float ax = 0.f, ay = 0.f;
    int e = e0;
    for (; e + 4 <= e1; e += 4) {
        int s0 = csr_src[e + 0];
        int s1 = csr_src[e + 1];
        int s2 = csr_src[e + 2];
        int s3 = csr_src[e + 3];
        bf16x2 v0 = *(const bf16x2*)(in + (size_t)s0 * 128 + c);
        bf16x2 v1 = *(const bf16x2*)(in + (size_t)s1 * 128 + c);
        bf16x2 v2 = *(const bf16x2*)(in + (size_t)s2 * 128 + c);
        bf16x2 v3 = *(const bf16x2*)(in + (size_t)s3 * 128 + c);
        ax += (float)v0[0] + (float)v1[0] + (float)v2[0] + (float)v3[0];
        ay += (float)v0[1] + (float)v1[1] + (float)v2[1] + (float)v3[1];
    }
    for (; e < e1; e++) {
        int s = csr_src[e];
        bf16x2 v = *(const bf16x2*)(in + (size_t)s * 128 + c);
        ax += (float)v[0];
        ay += (float)v[1];
    }
    float nd = norm[node];
    float cx = ax * nd, cy = ay * nd;
    bf16x2 o; o[0] = (bf16_t)cx; o[1] = (bf16_t)cy;
    *(bf16x2*)(out_c + (size_t)node * 128 + c) = o;
    if (SCALED) {
        bf16x2 s2v; s2v[0] = (bf16_t)(cx * nd); s2v[1] = (bf16_t)(cy * nd);
        *(bf16x2*)(out_s + (size_t)node * 128 + c) = s2v;
    }
}

// ---------------- MFMA concat-GEMM: out = relu([f0|f1|f2] @ W + b) ----------------
template <int NT, bool LAYER1>
__global__ __launch_bounds__(256) void gemm_mfma(const bf16_t* __restrict__ f0,
                                                 const bf16_t* __restrict__ f1,
                                                 const bf16_t* __restrict__ f2,
                                                 const bf16_t* __restrict__ Wp,
                                                 const float* __restrict__ bias,
                                                 const float* __restrict__ norm,
                                                 bf16_t* __restrict__ out_b,
                                                 bf16_t* __restrict__ out_s,
                                                 float* __restrict__ out_f, int M) {
    int wave = threadIdx.x >> 6;
    int lane = threadIdx.x & 63;
    int q = lane >> 4, ln = lane & 15;
    int row0 = blockIdx.x * 128 + wave * 32;

    f32x4 acc[2][NT] = {};
    const bf16_t* feats[3] = {f0, f1, f2};
    const bf16x8* Wf = (const bf16x8*)Wp;

#pragma unroll
    for (int kc = 0; kc < 12; kc++) {
        const bf16_t* A = feats[kc >> 2] + (size_t)(kc & 3) * 32 + q * 8;
        bf16x8 a0 = *(const bf16x8*)(A + (size_t)(row0 + ln) * 128);
        bf16x8 a1 = *(const bf16x8*)(A + (size_t)(row0 + 16 + ln) * 128);
        const bf16x8* Bp = Wf + (size_t)kc * NT * 64 + lane;
#pragma unroll
        for (int nt = 0; nt < NT; nt++) {
            bf16x8 b = Bp[nt * 64];
            acc[0][nt] = __builtin_amdgcn_mfma_f32_16x16x32_bf16(a0, b, acc[0][nt], 0, 0, 0);
            acc[1][nt] = __builtin_amdgcn_mfma_f32_16x16x32_bf16(a1, b, acc[1][nt], 0, 0, 0);
        }
    }

    float bv[NT];
#pragma unroll
    for (int nt = 0; nt < NT; nt++) bv[nt] = bias[nt * 16 + ln];

#pragma unroll
    for (int mt = 0; mt < 2; mt++) {
#pragma unroll
        for (int r = 0; r < 4; r++) {
            int row = row0 + mt * 16 + q * 4 + r;
            if (row >= M) continue;
            float nd = LAYER1 ? norm[row] : 0.f;
#pragma unroll
            for (int nt = 0; nt < NT; nt++) {
                int col = nt * 16 + ln;
                float val = fmaxf(acc[mt][nt][r] + bv[nt], 0.f);
                if (LAYER1) {
                    out_b[(size_t)row * 128 + col] = (bf16_t)val;
                    out_s[(size_t)row * 128 + col] = (bf16_t)(val * nd);
                } else {
                    out_f[(size_t)row * 64 + col] = val;
                }
            }
        }
    }
}

// ---------------- parallel per-graph max pool ----------------
// graph_id is sorted; wave scans 64 contiguous nodes, running max per lane,
// atomicMax flush at graph transitions. Values post-relu >= 0, so fp32 bits
// are order-isomorphic to uint -> integer atomicMax vs zeroed output is exact.
__global__ __launch_bounds__(256) void maxpool2(const float* __restrict__ hF,
                                                const int* __restrict__ gid,
                                                unsigned int* __restrict__ out, int n) {
    int wave = threadIdx.x >> 6;
    int lane = threadIdx.x & 63;
    int n0 = blockIdx.x * 256 + wave * 64;
    if (n0 >= n) return;
    int n1 = min(n0 + 64, n);
    int cur = gid[n0];
    float m = 0.f;
    int i = n0;
    for (; i + 4 <= n1; i += 4) {
        int g0 = gid[i + 0], g1 = gid[i + 1], g2 = gid[i + 2], g3 = gid[i + 3];
        float v0 = hF[(size_t)(i + 0) * 64 + lane];
        float v1 = hF[(size_t)(i + 1) * 64 + lane];
        float v2 = hF[(size_t)(i + 2) * 64 + lane];
        float v3 = hF[(size_t)(i + 3) * 64 + lane];
        if (g0 != cur) { atomicMax(&out[cur * 64 + lane], __float_as_uint(m)); cur = g0; m = v0; } else m = fmaxf(m, v0);
        if (g1 != cur) { atomicMax(&out[cur * 64 + lane], __float_as_uint(m)); cur = g1; m = v1; } else m = fmaxf(m, v1);
        if (g2 != cur) { atomicMax(&out[cur * 64 + lane], __float_as_uint(m)); cur = g2; m = v2; } else m = fmaxf(m, v2);
        if (g3 != cur) { atomicMax(&out[cur * 64 + lane], __float_as_uint(m)); cur = g3; m = v3; } else m = fmaxf(m, v3);
    }
    for (; i < n1; i++) {
        int g = gid[i];
        float v = hF[(size_t)i * 64 + lane];
        if (g != cur) { atomicMax(&out[cur * 64 + lane], __float_as_uint(m)); cur = g; m = v; }
        else m = fmaxf(m, v);
    }
    atomicMax(&out[cur * 64 + lane], __float_as_uint(m));
}

extern "C" void kernel_launch(void* const* d_in, const int* in_sizes, int n_in,
                              void* d_out, int out_size, void* d_ws, size_t ws_size,
                              hipStream_t stream) {
    const float* x  = (const float*)d_in[0];
    const float* W1 = (const float*)d_in[1];
    const float* b1 = (const float*)d_in[2];
    const float* W2 = (const float*)d_in[3];
    const float* b2 = (const float*)d_in[4];
    const int* src  = (const int*)d_in[5];
    const int* dst  = (const int*)d_in[6];
    const int* gid  = (const int*)d_in[7];
    float* out = (float*)d_out;

    char* ws = (char*)d_ws;
    size_t off = 0;
    auto take = [&](size_t bytes) {
        void* p = ws + off;
        off = (off + bytes + 255) & ~(size_t)255;
        return p;
    };
    int* deg     = (int*)take((size_t)N_NODES * 4);
    int* cursor  = (int*)take((size_t)N_NODES * 4);
    size_t zero_bytes = off;
    float* norm  = (float*)take((size_t)N_NODES * 4);
    int* row_off = (int*)take((size_t)(N_NODES + 1) * 4);
    int* partial = (int*)take(64 * 4);
    int* csr_src = (int*)take((size_t)N_EDGES * 4);
    bf16_t* Wp1  = (bf16_t*)take((size_t)384 * 128 * 2);
    bf16_t* Wp2  = (bf16_t*)take((size_t)384 * 64 * 2);
    bf16_t* B0 = (bf16_t*)take((size_t)M_PAD * 128 * 2);  // xb      -> hF (fp32 64c)
    bf16_t* B1 = (bf16_t*)take((size_t)M_PAD * 128 * 2);  // xs      -> hL1s
    bf16_t* B2 = (bf16_t*)take((size_t)M_PAD * 128 * 2);  // c1b     -> d1b
    bf16_t* B3 = (bf16_t*)take((size_t)M_PAD * 128 * 2);  // c2b     -> d2b
    bf16_t* B4 = (bf16_t*)take((size_t)M_PAD * 128 * 2);  // u1b     -> u2b
    bf16_t* B5 = (bf16_t*)take((size_t)M_PAD * 128 * 2);  // hL1b
    (void)ws_size; (void)in_sizes; (void)n_in; (void)out_size;

    hipMemsetAsync(d_ws, 0, zero_bytes, stream);
    hipMemsetAsync(d_out, 0, (size_t)N_GRAPHS * 64 * 4, stream);

    degk<<<(N_EDGES + 255) / 256, 256, 0, stream>>>(dst, deg, N_EDGES);
    normk<<<(N_NODES + 255) / 256, 256, 0, stream>>>(deg, norm, N_NODES);

    int nchunks = (N_NODES + 1023) / 1024;
    scan1<<<nchunks, 1024, 0, stream>>>(deg, row_off, partial, N_NODES);
    scan2<<<1, 64, 0, stream>>>(partial, nchunks);
    scan3<<<(N_NODES + 255) / 256, 256, 0, stream>>>(row_off, partial, N_NODES);
    scatterk<<<(N_EDGES + 255) / 256, 256, 0, stream>>>(src, dst, row_off, cursor, csr_src, N_EDGES);

    prescale<<<(N_NODES * 64 + 255) / 256, 256, 0, stream>>>(x, norm, B0, B1, N_NODES);
    permW<<<(384 * 128 + 255) / 256, 256, 0, stream>>>(W1, Wp1, 384, 128);
    permW<<<(384 * 64 + 255) / 256, 256, 0, stream>>>(W2, Wp2, 384, 64);

    int spmm_grid = (N_NODES + 3) / 4;
    int gemm_grid = M_PAD / 128;  // 392
    // layer 1: hops
    spmm_bf16<true><<<spmm_grid, 256, 0, stream>>>(B1, B2, B4, norm, row_off, csr_src, N_NODES);
    spmm_bf16<false><<<spmm_grid, 256, 0, stream>>>(B4, B3, nullptr, norm, row_off, csr_src, N_NODES);
    // layer 1: GEMM -> hL1b (B5), hL1s (B1)
    gemm_mfma<8, true><<<gemm_grid, 256, 0, stream>>>(B0, B2, B3, Wp1, b1, norm, B5, B1, nullptr, N_NODES);
    // layer 2: hops
    spmm_bf16<true><<<spmm_grid, 256, 0, stream>>>(B1, B2, B4, norm, row_off, csr_src, N_NODES);
    spmm_bf16<false><<<spmm_grid, 256, 0, stream>>>(B4, B3, nullptr, norm, row_off, csr_src, N_NODES);
    // layer 2: GEMM -> hF (B0 as fp32, 64 cols)
    gemm_mfma<4, false><<<gemm_grid, 256, 0, stream>>>(B5, B2, B3, Wp2, b2, nullptr, nullptr, nullptr, (float*)B0, N_NODES);
    // readout
    maxpool2<<<(N_NODES + 255) / 256, 256, 0, stream>>>((const float*)B0, gid, (unsigned int*)out, N_NODES);
}

// Round 4
// 308.802 us; speedup vs baseline: 2.0042x; 1.1091x over previous
//
#include <hip/hip_runtime.h>
#include <hip/hip_bf16.h>

#define N_NODES 50000
#define N_EDGES 600000
#define N_GRAPHS 100
#define M_PAD 50176  // 392 * 128

typedef __bf16 bf16_t;
typedef __attribute__((ext_vector_type(8))) __bf16 bf16x8;
typedef __attribute__((ext_vector_type(2))) __bf16 bf16x2;
typedef __attribute__((ext_vector_type(4))) float f32x4;

// ---------------- degree / norm ----------------
__global__ void degk(const int* __restrict__ dst, int* __restrict__ deg, int n) {
    int i = blockIdx.x * 256 + threadIdx.x;
    if (i < n) atomicAdd(&deg[dst[i]], 1);
}

__global__ void normk(const int* __restrict__ deg, float* __restrict__ norm, int n) {
    int i = blockIdx.x * 256 + threadIdx.x;
    if (i < n) {
        float d = fmaxf((float)deg[i], 1.0f);
        norm[i] = 1.0f / sqrtf(d);
    }
}

// ---------------- hierarchical exclusive scan (row offsets) ----------------
__global__ __launch_bounds__(1024) void scan1(const int* __restrict__ deg,
                                              int* __restrict__ row_off,
                                              int* __restrict__ partial, int n) {
    __shared__ int buf[1024];
    int i = blockIdx.x * 1024 + threadIdx.x;
    int v = (i < n) ? deg[i] : 0;
    buf[threadIdx.x] = v;
    __syncthreads();
    for (int off = 1; off < 1024; off <<= 1) {
        int t = (threadIdx.x >= off) ? buf[threadIdx.x - off] : 0;
        __syncthreads();
        buf[threadIdx.x] += t;
        __syncthreads();
    }
    if (i < n) row_off[i + 1] = buf[threadIdx.x];
    if (threadIdx.x == 1023) partial[blockIdx.x] = buf[1023];
}

__global__ void scan2(int* __restrict__ partial, int nchunks) {
    int lane = threadIdx.x;
    int v = (lane < nchunks) ? partial[lane] : 0;
    for (int off = 1; off < 64; off <<= 1) {
        int t = __shfl_up(v, off, 64);
        if (lane >= off) v += t;
    }
    int ex = __shfl_up(v, 1, 64);
    if (lane == 0) ex = 0;
    if (lane < nchunks) partial[lane] = ex;
}

__global__ void scan3(int* __restrict__ row_off, const int* __restrict__ partial, int n) {
    int i = blockIdx.x * 256 + threadIdx.x;
    if (i == 0) row_off[0] = 0;
    if (i < n) row_off[i + 1] += partial[i >> 10];
}

// ---------------- CSR scatter ----------------
__global__ void scatterk(const int* __restrict__ src, const int* __restrict__ dst,
                         const int* __restrict__ row_off, int* __restrict__ cursor,
                         int* __restrict__ csr_src, int n) {
    int e = blockIdx.x * 256 + threadIdx.x;
    if (e >= n) return;
    int d = dst[e];
    int pos = atomicAdd(&cursor[d], 1);
    csr_src[row_off[d] + pos] = src[e];
}

// ---------------- prescale: xb = bf16(x), xs = bf16(x*norm) ----------------
__global__ void prescale(const float* __restrict__ x, const float* __restrict__ norm,
                         bf16_t* __restrict__ xb, bf16_t* __restrict__ xs, int n) {
    int i = blockIdx.x * 256 + threadIdx.x;
    if (i >= n * 64) return;
    int node = i >> 6;
    int c = (i & 63) * 2;
    float2 v = *(const float2*)(x + (size_t)node * 128 + c);
    float nd = norm[node];
    bf16x2 vb; vb[0] = (bf16_t)v.x; vb[1] = (bf16_t)v.y;
    bf16x2 vs; vs[0] = (bf16_t)(v.x * nd); vs[1] = (bf16_t)(v.y * nd);
    *(bf16x2*)(xb + (size_t)node * 128 + c) = vb;
    *(bf16x2*)(xs + (size_t)node * 128 + c) = vs;
}

// ---------------- W permute to MFMA B-fragment layout + bf16 ----------------
__global__ void permW(const float* __restrict__ W, bf16_t* __restrict__ Wp, int K, int N) {
    int i = blockIdx.x * 256 + threadIdx.x;
    if (i >= K * N) return;
    int k = i / N, n = i - k * N;
    int kt = k >> 5, q = (k >> 3) & 3, j = k & 7;
    int nt = n >> 4, ln = n & 15;
    int lane = q * 16 + ln;
    Wp[(((size_t)kt * (N >> 4) + nt) * 64 + lane) * 8 + j] = (bf16_t)W[i];
}

// ---------------- SpMM: 16 lanes per dst node, bf16x8 (16B) row chunks ----------------
// One wave instruction gathers 4 full rows (1KB). Edge-index loads are
// subgroup-uniform (HW broadcast). fp32 accumulate, unroll x4 for MLP.
template <bool SCALED>
__global__ __launch_bounds__(256) void spmm_bf16(const bf16_t* __restrict__ in,
                                                 bf16_t* __restrict__ out_c,
                                                 bf16_t* __restrict__ out_s,
                                                 const float* __restrict__ norm,
                                                 const int* __restrict__ row_off,
                                                 const int* __restrict__ csr_src, int n) {
    int tid = threadIdx.x;
    int sub = tid >> 4;   // 16 subgroups per block
    int l   = tid & 15;   // lane within subgroup: feats [l*8, l*8+8)
    int node = blockIdx.x * 16 + sub;
    if (node >= n) return;
    int e0 = row_off[node], e1 = row_off[node + 1];
    const bf16_t* col = in + l * 8;
    float acc[8] = {};
    int e = e0;
    for (; e + 4 <= e1; e += 4) {
        int s0 = csr_src[e + 0];
        int s1 = csr_src[e + 1];
        int s2 = csr_src[e + 2];
        int s3 = csr_src[e + 3];
        bf16x8 v0 = *(const bf16x8*)(col + (size_t)s0 * 128);
        bf16x8 v1 = *(const bf16x8*)(col + (size_t)s1 * 128);
        bf16x8 v2 = *(const bf16x8*)(col + (size_t)s2 * 128);
        bf16x8 v3 = *(const bf16x8*)(col + (size_t)s3 * 128);
#pragma unroll
        for (int j = 0; j < 8; j++)
            acc[j] += ((float)v0[j] + (float)v1[j]) + ((float)v2[j] + (float)v3[j]);
    }
    for (; e < e1; e++) {
        int s = csr_src[e];
        bf16x8 v = *(const bf16x8*)(col + (size_t)s * 128);
#pragma unroll
        for (int j = 0; j < 8; j++) acc[j] += (float)v[j];
    }
    float nd = norm[node];
    bf16x8 oc, os;
#pragma unroll
    for (int j = 0; j < 8; j++) {
        float c = acc[j] * nd;
        oc[j] = (bf16_t)c;
        os[j] = (bf16_t)(c * nd);
    }
    *(bf16x8*)(out_c + (size_t)node * 128 + l * 8) = oc;
    if (SCALED) *(bf16x8*)(out_s + (size_t)node * 128 + l * 8) = os;
}

// ---------------- MFMA concat-GEMM: out = relu([f0|f1|f2] @ W + b) ----------------
template <int NT, bool LAYER1>
__global__ __launch_bounds__(256) void gemm_mfma(const bf16_t* __restrict__ f0,
                                                 const bf16_t* __restrict__ f1,
                                                 const bf16_t* __restrict__ f2,
                                                 const bf16_t* __restrict__ Wp,
                                                 const float* __restrict__ bias,
                                                 const float* __restrict__ norm,
                                                 bf16_t* __restrict__ out_b,
                                                 bf16_t* __restrict__ out_s,
                                                 float* __restrict__ out_f, int M) {
    int wave = threadIdx.x >> 6;
    int lane = threadIdx.x & 63;
    int q = lane >> 4, ln = lane & 15;
    int row0 = blockIdx.x * 128 + wave * 32;

    f32x4 acc[2][NT] = {};
    const bf16_t* feats[3] = {f0, f1, f2};
    const bf16x8* Wf = (const bf16x8*)Wp;

#pragma unroll
    for (int kc = 0; kc < 12; kc++) {
        const bf16_t* A = feats[kc >> 2] + (size_t)(kc & 3) * 32 + q * 8;
        bf16x8 a0 = *(const bf16x8*)(A + (size_t)(row0 + ln) * 128);
        bf16x8 a1 = *(const bf16x8*)(A + (size_t)(row0 + 16 + ln) * 128);
        const bf16x8* Bp = Wf + (size_t)kc * NT * 64 + lane;
#pragma unroll
        for (int nt = 0; nt < NT; nt++) {
            bf16x8 b = Bp[nt * 64];
            acc[0][nt] = __builtin_amdgcn_mfma_f32_16x16x32_bf16(a0, b, acc[0][nt], 0, 0, 0);
            acc[1][nt] = __builtin_amdgcn_mfma_f32_16x16x32_bf16(a1, b, acc[1][nt], 0, 0, 0);
        }
    }

    float bv[NT];
#pragma unroll
    for (int nt = 0; nt < NT; nt++) bv[nt] = bias[nt * 16 + ln];

#pragma unroll
    for (int mt = 0; mt < 2; mt++) {
#pragma unroll
        for (int r = 0; r < 4; r++) {
            int row = row0 + mt * 16 + q * 4 + r;
            if (row >= M) continue;
            float nd = LAYER1 ? norm[row] : 0.f;
#pragma unroll
            for (int nt = 0; nt < NT; nt++) {
                int col = nt * 16 + ln;
                float val = fmaxf(acc[mt][nt][r] + bv[nt], 0.f);
                if (LAYER1) {
                    out_b[(size_t)row * 128 + col] = (bf16_t)val;
                    out_s[(size_t)row * 128 + col] = (bf16_t)(val * nd);
                } else {
                    out_f[(size_t)row * 64 + col] = val;
                }
            }
        }
    }
}

// ---------------- parallel per-graph max pool ----------------
__global__ __launch_bounds__(256) void maxpool2(const float* __restrict__ hF,
                                                const int* __restrict__ gid,
                                                unsigned int* __restrict__ out, int n) {
    int wave = threadIdx.x >> 6;
    int lane = threadIdx.x & 63;
    int n0 = blockIdx.x * 256 + wave * 64;
    if (n0 >= n) return;
    int n1 = min(n0 + 64, n);
    int cur = gid[n0];
    float m = 0.f;
    int i = n0;
    for (; i + 4 <= n1; i += 4) {
        int g0 = gid[i + 0], g1 = gid[i + 1], g2 = gid[i + 2], g3 = gid[i + 3];
        float v0 = hF[(size_t)(i + 0) * 64 + lane];
        float v1 = hF[(size_t)(i + 1) * 64 + lane];
        float v2 = hF[(size_t)(i + 2) * 64 + lane];
        float v3 = hF[(size_t)(i + 3) * 64 + lane];
        if (g0 != cur) { atomicMax(&out[cur * 64 + lane], __float_as_uint(m)); cur = g0; m = v0; } else m = fmaxf(m, v0);
        if (g1 != cur) { atomicMax(&out[cur * 64 + lane], __float_as_uint(m)); cur = g1; m = v1; } else m = fmaxf(m, v1);
        if (g2 != cur) { atomicMax(&out[cur * 64 + lane], __float_as_uint(m)); cur = g2; m = v2; } else m = fmaxf(m, v2);
        if (g3 != cur) { atomicMax(&out[cur * 64 + lane], __float_as_uint(m)); cur = g3; m = v3; } else m = fmaxf(m, v3);
    }
    for (; i < n1; i++) {
        int g = gid[i];
        float v = hF[(size_t)i * 64 + lane];
        if (g != cur) { atomicMax(&out[cur * 64 + lane], __float_as_uint(m)); cur = g; m = v; }
        else m = fmaxf(m, v);
    }
    atomicMax(&out[cur * 64 + lane], __float_as_uint(m));
}

extern "C" void kernel_launch(void* const* d_in, const int* in_sizes, int n_in,
                              void* d_out, int out_size, void* d_ws, size_t ws_size,
                              hipStream_t stream) {
    const float* x  = (const float*)d_in[0];
    const float* W1 = (const float*)d_in[1];
    const float* b1 = (const float*)d_in[2];
    const float* W2 = (const float*)d_in[3];
    const float* b2 = (const float*)d_in[4];
    const int* src  = (const int*)d_in[5];
    const int* dst  = (const int*)d_in[6];
    const int* gid  = (const int*)d_in[7];
    float* out = (float*)d_out;

    char* ws = (char*)d_ws;
    size_t off = 0;
    auto take = [&](size_t bytes) {
        void* p = ws + off;
        off = (off + bytes + 255) & ~(size_t)255;
        return p;
    };
    int* deg     = (int*)take((size_t)N_NODES * 4);
    int* cursor  = (int*)take((size_t)N_NODES * 4);
    size_t zero_bytes = off;
    float* norm  = (float*)take((size_t)N_NODES * 4);
    int* row_off = (int*)take((size_t)(N_NODES + 1) * 4);
    int* partial = (int*)take(64 * 4);
    int* csr_src = (int*)take((size_t)N_EDGES * 4);
    bf16_t* Wp1  = (bf16_t*)take((size_t)384 * 128 * 2);
    bf16_t* Wp2  = (bf16_t*)take((size_t)384 * 64 * 2);
    bf16_t* B0 = (bf16_t*)take((size_t)M_PAD * 128 * 2);  // xb      -> hF (fp32 64c)
    bf16_t* B1 = (bf16_t*)take((size_t)M_PAD * 128 * 2);  // xs      -> hL1s
    bf16_t* B2 = (bf16_t*)take((size_t)M_PAD * 128 * 2);  // c1b     -> d1b
    bf16_t* B3 = (bf16_t*)take((size_t)M_PAD * 128 * 2);  // c2b     -> d2b
    bf16_t* B4 = (bf16_t*)take((size_t)M_PAD * 128 * 2);  // u1b     -> u2b
    bf16_t* B5 = (bf16_t*)take((size_t)M_PAD * 128 * 2);  // hL1b
    (void)ws_size; (void)in_sizes; (void)n_in; (void)out_size;

    hipMemsetAsync(d_ws, 0, zero_bytes, stream);
    hipMemsetAsync(d_out, 0, (size_t)N_GRAPHS * 64 * 4, stream);

    degk<<<(N_EDGES + 255) / 256, 256, 0, stream>>>(dst, deg, N_EDGES);
    normk<<<(N_NODES + 255) / 256, 256, 0, stream>>>(deg, norm, N_NODES);

    int nchunks = (N_NODES + 1023) / 1024;
    scan1<<<nchunks, 1024, 0, stream>>>(deg, row_off, partial, N_NODES);
    scan2<<<1, 64, 0, stream>>>(partial, nchunks);
    scan3<<<(N_NODES + 255) / 256, 256, 0, stream>>>(row_off, partial, N_NODES);
    scatterk<<<(N_EDGES + 255) / 256, 256, 0, stream>>>(src, dst, row_off, cursor, csr_src, N_EDGES);

    prescale<<<(N_NODES * 64 + 255) / 256, 256, 0, stream>>>(x, norm, B0, B1, N_NODES);
    permW<<<(384 * 128 + 255) / 256, 256, 0, stream>>>(W1, Wp1, 384, 128);
    permW<<<(384 * 64 + 255) / 256, 256, 0, stream>>>(W2, Wp2, 384, 64);

    int spmm_grid = (N_NODES + 15) / 16;  // 16 nodes per block
    int gemm_grid = M_PAD / 128;          // 392
    // layer 1: hops
    spmm_bf16<true><<<spmm_grid, 256, 0, stream>>>(B1, B2, B4, norm, row_off, csr_src, N_NODES);
    spmm_bf16<false><<<spmm_grid, 256, 0, stream>>>(B4, B3, nullptr, norm, row_off, csr_src, N_NODES);
    // layer 1: GEMM -> hL1b (B5), hL1s (B1)
    gemm_mfma<8, true><<<gemm_grid, 256, 0, stream>>>(B0, B2, B3, Wp1, b1, norm, B5, B1, nullptr, N_NODES);
    // layer 2: hops
    spmm_bf16<true><<<spmm_grid, 256, 0, stream>>>(B1, B2, B4, norm, row_off, csr_src, N_NODES);
    spmm_bf16<false><<<spmm_grid, 256, 0, stream>>>(B4, B3, nullptr, norm, row_off, csr_src, N_NODES);
    // layer 2: GEMM -> hF (B0 as fp32, 64 cols)
    gemm_mfma<4, false><<<gemm_grid, 256, 0, stream>>>(B5, B2, B3, Wp2, b2, nullptr, nullptr, nullptr, (float*)B0, N_NODES);
    // readout
    maxpool2<<<(N_NODES + 255) / 256, 256, 0, stream>>>((const float*)B0, gid, (unsigned int*)out, N_NODES);
}